// Round 5
// baseline (436.683 us; speedup 1.0000x reference)
//
#include <hip/hip_runtime.h>
#include <hip/hip_bf16.h>
#include <hip/hip_fp16.h>
#include <hip/hip_fp8.h>

// DeformableAttention on MI355X.
// prep(weights^T bf16) -> gemm_bf16(q) -> fused conv+LN+GELU+pos+sample ->
// gemm_bf16(kv; K->kb, V->vtb transposed) -> fused flash-attn v6
// (kt-SPLIT: 8-wave blocks, waves 0-3 do kt 0-7 / waves 4-7 do kt 8-15 for
// the same rows, partials summed via LDS at the end -> 32 waves/CU;
// swapped QK^T; vectorized wave-local P; zero barriers in kt loop)
// -> gemm_bf16(out,+bias)

#define EPS_ 1e-5f
#define ASCALE 0.17677669529663687f      // 1/sqrt(32)
#define LOG2E  1.4426950408889634f

typedef __attribute__((ext_vector_type(8))) short bf16x8;
typedef __attribute__((ext_vector_type(4))) float f32x4;

__device__ __forceinline__ short f2bf(float f) {
  union { float f; unsigned u; } v; v.f = f;
  unsigned r = (v.u + 0x7fffu + ((v.u >> 16) & 1u)) >> 16;  // RNE
  return (short)r;
}
__device__ __forceinline__ unsigned pk2bf(float a, float b) {
  union { __hip_bfloat162 h; unsigned u; } v;
  v.h = __float22bfloat162_rn(make_float2(a, b));
  return v.u;
}
__device__ __forceinline__ float exp2_fast(float x) {
  return __builtin_amdgcn_exp2f(x);
}

// fp8 e4m3 quad pack/unpack: HW v_cvt_pk_* on gfx950, sw fallback otherwise.
__device__ __forceinline__ unsigned pack_fp8_quad(float v00, float v10,
                                                  float v01, float v11) {
#if __has_builtin(__builtin_amdgcn_cvt_pk_fp8_f32)
  int r = 0;
  r = __builtin_amdgcn_cvt_pk_fp8_f32(v00, v10, r, false);  // bytes 0,1
  r = __builtin_amdgcn_cvt_pk_fp8_f32(v01, v11, r, true);   // bytes 2,3
  return (unsigned)r;
#else
  __hip_fp8x2_e4m3 elo(make_float2(v00, v10));
  __hip_fp8x2_e4m3 ehi(make_float2(v01, v11));
  return (unsigned)(unsigned short)elo.__x |
         ((unsigned)(unsigned short)ehi.__x << 16);
#endif
}
__device__ __forceinline__ void unpack_fp8_quad(unsigned u, float& g00,
                                                float& g10, float& g01,
                                                float& g11) {
#if __has_builtin(__builtin_amdgcn_cvt_pk_f32_fp8)
  auto ga = __builtin_amdgcn_cvt_pk_f32_fp8((int)u, false);  // (v00, v10)
  auto gb = __builtin_amdgcn_cvt_pk_f32_fp8((int)u, true);   // (v01, v11)
  g00 = ga[0]; g10 = ga[1]; g01 = gb[0]; g11 = gb[1];
#else
  __hip_fp8x2_e4m3 plo, phi;
  plo.__x = (__hip_fp8x2_storage_t)(unsigned short)(u & 0xffffu);
  phi.__x = (__hip_fp8x2_storage_t)(unsigned short)(u >> 16);
  float2 fa = (float2)plo, fb = (float2)phi;
  g00 = fa.x; g10 = fa.y; g01 = fb.x; g11 = fb.y;
#endif
}

// ---------------------------------------------------------------------------
// Weight prep: Wkvt[n][k]=bf16(Wkv[k][n]); Woutt, Wqt likewise.
// ---------------------------------------------------------------------------
__global__ __launch_bounds__(256) void prep_weights(
    const float* __restrict__ Wkv, const float* __restrict__ Wout,
    const float* __restrict__ Wq, short* __restrict__ Wkvt,
    short* __restrict__ Woutt, short* __restrict__ Wqt)
{
  int bid = blockIdx.x, k = threadIdx.x;
  if (bid < 512) Wkvt[bid * 256 + k] = f2bf(Wkv[k * 512 + bid]);
  else if (bid < 768) { int n = bid - 512; Woutt[n * 256 + k] = f2bf(Wout[k * 256 + n]); }
  else { int n = bid - 768; Wqt[n * 256 + k] = f2bf(Wq[k * 256 + n]); }
}

// ---------------------------------------------------------------------------
// bf16 MFMA GEMM: C[M,N] = A[M,256] @ Bt[N,256]^T (+bias), with prefetch.
// If vt != null: blocks with n0 >= 256 write V^T to vt[b][d][j] (bf16)
// via an LDS transpose (coalesced b128 stores), and skip the normal C write.
// ---------------------------------------------------------------------------
__global__ __launch_bounds__(256) void gemm_bf16(
    const short* __restrict__ Ab, const float* __restrict__ Af,
    const short* __restrict__ Bt,
    float* __restrict__ Cf, short* __restrict__ Cb,
    const float* __restrict__ bias, int N, short* __restrict__ vt)
{
  __shared__ __align__(16) short smem[5120];   // As(2560) | Bs(2560); reused as sV[64][72]
  short* As = smem;
  short* Bs = smem + 2560;
  const int t = threadIdx.x;
  const int n0 = blockIdx.x << 6, m0 = blockIdx.y << 6;
  const int wv = t >> 6, l16 = t & 15, quad = (t & 63) >> 4;
  const int row = t >> 2, koff = (t & 3) << 3;

  auto loadA = [&](int k0) -> bf16x8 {
    if (Af) {
      const float* src = &Af[(size_t)(m0 + row) * 256 + k0 + koff];
      float4 f0 = *(const float4*)src;
      float4 f1 = *(const float4*)(src + 4);
      union { unsigned u[4]; bf16x8 v; } c;
      c.u[0] = pk2bf(f0.x, f0.y); c.u[1] = pk2bf(f0.z, f0.w);
      c.u[2] = pk2bf(f1.x, f1.y); c.u[3] = pk2bf(f1.z, f1.w);
      return c.v;
    }
    return *(const bf16x8*)&Ab[(size_t)(m0 + row) * 256 + k0 + koff];
  };

  f32x4 acc[4] = {};
  bf16x8 av = loadA(0);
  bf16x8 bv = *(const bf16x8*)&Bt[(size_t)(n0 + row) * 256 + koff];
  for (int k0 = 0; k0 < 256; k0 += 32) {
    __syncthreads();  // prior-iter frag reads done before overwrite
    *(bf16x8*)&As[row * 40 + koff] = av;
    *(bf16x8*)&Bs[row * 40 + koff] = bv;
    __syncthreads();
    if (k0 + 32 < 256) {  // prefetch next chunk before MFMA section
      av = loadA(k0 + 32);
      bv = *(const bf16x8*)&Bt[(size_t)(n0 + row) * 256 + k0 + 32 + koff];
    }
    bf16x8 a = *(const bf16x8*)&As[((wv << 4) + l16) * 40 + (quad << 3)];
#pragma unroll
    for (int jt = 0; jt < 4; jt++) {
      bf16x8 bb = *(const bf16x8*)&Bs[((jt << 4) + l16) * 40 + (quad << 3)];
      acc[jt] = __builtin_amdgcn_mfma_f32_16x16x32_bf16(a, bb, acc[jt], 0, 0, 0);
    }
  }

  if (vt && n0 >= 256) {
    // ---- V^T epilogue: stage C-tile into LDS as [d][j], store coalesced.
    __syncthreads();                     // done with As/Bs MFMA reads
    short* sV = smem;                    // [64][72] shorts (9216 B <= 10240)
#pragma unroll
    for (int jt = 0; jt < 4; jt++) {
#pragma unroll
      for (int r = 0; r < 4; r++) {
        int nl = (jt << 4) + l16;                 // d-local
        int ml = (wv << 4) + (quad << 2) + r;     // j-local
        sV[nl * 72 + ml] = f2bf(acc[jt][r]);
      }
    }
    __syncthreads();
    int dl = t >> 2, js0 = (t & 3) << 3;
    bf16x8 v0 = *(const bf16x8*)&sV[dl * 72 + js0];
    bf16x8 v1 = *(const bf16x8*)&sV[dl * 72 + js0 + 32];
    int bb = m0 >> 10, j0 = m0 & 1023;
    size_t base = ((size_t)((bb << 8) + (n0 - 256) + dl) << 10) + j0;
    *(bf16x8*)&vt[base + js0]      = v0;
    *(bf16x8*)&vt[base + js0 + 32] = v1;
    return;
  }

#pragma unroll
  for (int jt = 0; jt < 4; jt++) {
#pragma unroll
    for (int r = 0; r < 4; r++) {
      int mrow = m0 + (wv << 4) + (quad << 2) + r;
      int ncol = n0 + (jt << 4) + l16;
      float v = acc[jt][r];
      if (bias) v += bias[ncol];
      if (Cf) Cf[(size_t)mrow * N + ncol] = v;
      else    Cb[(size_t)mrow * N + ncol] = f2bf(v);
    }
  }
}

// ---------------------------------------------------------------------------
// Fused: conv5x5 depthwise + LN(128) + GELU + @Woff + tanh -> pos, then
// grid_sample of this pixel's group channels -> xs (bf16). Wave per (b,g,pix).
// ---------------------------------------------------------------------------
__global__ __launch_bounds__(256) void conv_pos_sample_kernel(
    const float* __restrict__ q, const float* __restrict__ conv_w,
    const float* __restrict__ conv_b, const float* __restrict__ ln_g,
    const float* __restrict__ ln_b, const float* __restrict__ Woff,
    float* __restrict__ pos, short* __restrict__ xsb)
{
  const int p = (blockIdx.x << 2) + (threadIdx.x >> 6);
  const int lane = threadIdx.x & 63;
  const int bg = p >> 10, pix = p & 1023;
  const int hh = pix >> 5, ww = pix & 31;
  const int b = bg >> 1, g = bg & 1;
  const int c0 = lane << 1;

  float2 cb = *(const float2*)&conv_b[c0];
  float a0 = cb.x, a1 = cb.y;
  const float* w0 = conv_w + c0 * 25;
  const float* w1 = w0 + 25;
#pragma unroll
  for (int dy = 0; dy < 5; dy++) {
    int y = hh + dy - 2;
    if ((unsigned)y < 32u) {
#pragma unroll
      for (int dx = 0; dx < 5; dx++) {
        int x = ww + dx - 2;
        if ((unsigned)x < 32u) {
          float2 qv = *(const float2*)&q[(size_t)((b << 10) + (y << 5) + x) * 256 + (g << 7) + c0];
          a0 = fmaf(qv.x, w0[dy * 5 + dx], a0);
          a1 = fmaf(qv.y, w1[dy * 5 + dx], a1);
        }
      }
    }
  }
  float s1 = a0 + a1, s2 = a0 * a0 + a1 * a1;
#pragma unroll
  for (int o = 32; o; o >>= 1) { s1 += __shfl_xor(s1, o); s2 += __shfl_xor(s2, o); }
  float mu = s1 * (1.f / 128.f);
  float inv = rsqrtf(fmaf(-mu, mu, s2 * (1.f / 128.f)) + EPS_);
  float2 lg = *(const float2*)&ln_g[c0];
  float2 lb = *(const float2*)&ln_b[c0];
  float v0 = (a0 - mu) * inv * lg.x + lb.x;
  float v1 = (a1 - mu) * inv * lg.y + lb.y;
  float ge0 = 0.5f * v0 * (1.f + erff(v0 * 0.70710678118654752f));
  float ge1 = 0.5f * v1 * (1.f + erff(v1 * 0.70710678118654752f));
  float2 W0 = *(const float2*)&Woff[c0 * 2];
  float2 W1 = *(const float2*)&Woff[c0 * 2 + 2];
  float o0 = ge0 * W0.x + ge1 * W1.x;
  float o1 = ge0 * W0.y + ge1 * W1.y;
#pragma unroll
  for (int o = 32; o; o >>= 1) { o0 += __shfl_xor(o0, o); o1 += __shfl_xor(o1, o); }
  float py = tanhf(o0) * 0.0625f + ((hh + 0.5f) * 0.0625f - 1.f);
  float px = tanhf(o1) * 0.0625f + ((ww + 0.5f) * 0.0625f - 1.f);
  if (lane == 0)
    ((float2*)pos)[(bg << 10) + pix] = make_float2(py, px);

  float x = (px + 1.f) * 15.5f;
  float y = (py + 1.f) * 15.5f;
  float x0f = floorf(x), y0f = floorf(y);
  int ix0 = (int)x0f, iy0 = (int)y0f;
  float fx = x - x0f, fy = y - y0f;
  float ac0 = 0.f, ac1 = 0.f;
#pragma unroll
  for (int dy = 0; dy < 2; dy++) {
#pragma unroll
    for (int dx = 0; dx < 2; dx++) {
      int yi = iy0 + dy, xi = ix0 + dx;
      float w = (dy ? fy : 1.f - fy) * (dx ? fx : 1.f - fx);
      if ((unsigned)yi < 32u && (unsigned)xi < 32u) {
        float2 qv = *(const float2*)&q[(size_t)((b << 10) + (yi << 5) + xi) * 256 + (g << 7) + c0];
        ac0 = fmaf(w, qv.x, ac0);
        ac1 = fmaf(w, qv.y, ac1);
      }
    }
  }
  *(unsigned*)&xsb[(size_t)((b << 10) + pix) * 256 + (g << 7) + c0] = pk2bf(ac0, ac1);
}

// ---------------------------------------------------------------------------
// Fused attention v6: one block = (64-row i-tile, head, batch), 512 threads
// (8 waves).  kt-SPLIT: wave w -> wv2 = w&3 picks the 16-row subtile,
// half = w>>2 picks kt range [half*8, half*8+8).  Fixed-m softmax in exp2
// domain means partial (Oacc, lacc) sum linearly: half-1 waves dump partials
// to LDS (aliased onto Pw, double-barriered), half-0 waves add + epilogue.
// 8192 waves total = 32 waves/CU (2x v5's 16).  Swapped QK^T, wave-local P,
// zero barriers inside the kt loop.  LDS 36 KB -> 4 blocks/CU.
// ---------------------------------------------------------------------------
__global__ __launch_bounds__(512, 8) void attn_kernel(
    const float* __restrict__ q, const short* __restrict__ kb,
    const short* __restrict__ vtb, const float* __restrict__ pos,
    const float* __restrict__ rpe, short* __restrict__ ao)
{
  const int it = blockIdx.x, h = blockIdx.y, b = blockIdx.z;
  const int g = h >> 2, t = threadIdx.x;
  const int w = t >> 6, l16 = t & 15, quad = (t & 63) >> 4;
  const int lane = t & 63;
  const int wv2 = w & 3, half = w >> 2;

  __shared__ __align__(16) unsigned rpe8[64 * 64];  // 16 KB fp8 quad table
  __shared__ __align__(16) short Pw[8][1024];       // 16 KB wave-private P[16][64]
  __shared__ __align__(16) float2 posW[8][64];      // 4 KB wave-private pos

  // ---- stage fp8 rpe quad table over the reachable window (origin +31).
  {
    const float* rp = rpe + h * 3969;
    for (int i = t; i < 4096; i += 512) {
      int ty = i >> 6, tx = i & 63;
      float v00 = 0.f, v10 = 0.f, v01 = 0.f, v11 = 0.f;
      if (tx <= 62) {
        if (ty <= 62) v00 = rp[ty * 63 + tx] * LOG2E;
        if (ty <= 61) v10 = rp[(ty + 1) * 63 + tx] * LOG2E;
      }
      if (tx <= 61) {
        if (ty <= 62) v01 = rp[ty * 63 + tx + 1] * LOG2E;
        if (ty <= 61) v11 = rp[(ty + 1) * 63 + tx + 1] * LOG2E;
      }
      rpe8[i] = pack_fp8_quad(v00, v10, v01, v11);
    }
  }

  // ---- Q B-frag from global (once), scaled by ASCALE*LOG2E.
  const int row0 = (it << 6) + (wv2 << 4);
  bf16x8 aq;
  {
    const float* src = q + (size_t)((b << 10) + row0 + l16) * 256 + (h << 5) + (quad << 3);
    float4 f0 = *(const float4*)src;
    float4 f1 = *(const float4*)(src + 4);
    const float sc = ASCALE * LOG2E;
    union { unsigned u[4]; bf16x8 v; } c;
    c.u[0] = pk2bf(f0.x * sc, f0.y * sc); c.u[1] = pk2bf(f0.z * sc, f0.w * sc);
    c.u[2] = pk2bf(f1.x * sc, f1.y * sc); c.u[3] = pk2bf(f1.z * sc, f1.w * sc);
    aq = c.v;
  }

  // sampling coords (origin +31): i = row0 + l16; hh = row0>>5 wave-uniform
  const float ayc = 15.5f * (((row0 >> 5) + 0.5f) * 0.0625f - 1.f) + 31.f;
  const int ww_i = ((wv2 & 1) << 4) + l16;
  const float axl = 15.5f * ((ww_i + 0.5f) * 0.0625f - 1.f) + 31.f;

  bf16x8 vones;
#pragma unroll
  for (int i = 0; i < 8; i++) vones[i] = (short)0x3F80;  // bf16 1.0

  // wave-private P buffer, XOR-swizzled rows (row stride 128 B)
  char* pw = (char*)&Pw[w][0];
  const int pwrow = l16 << 7;
  const int swz = (l16 & 7) << 4;

  // ---- load helpers (K 4 frags, V 4 frags, pos) ----
  auto loadKf = [&](int kt, bf16x8* kf) {
    const int jb = kt << 6;
#pragma unroll
    for (int jt = 0; jt < 4; jt++)
      kf[jt] = *(const bf16x8*)&kb[(size_t)((b << 10) + jb + (jt << 4) + l16) * 256 + (h << 5) + (quad << 3)];
  };
  auto loadVf = [&](int kt, bf16x8* vf) {
    const int jb = kt << 6;
#pragma unroll
    for (int dt = 0; dt < 2; dt++) {
      const short* vb = &vtb[((size_t)((b << 8) + (h << 5) + (dt << 4) + l16) << 10) + jb + (quad << 3)];
      vf[dt * 2]     = *(const bf16x8*)vb;          // j-half 0
      vf[dt * 2 + 1] = *(const bf16x8*)(vb + 32);   // j-half 1
    }
  };
  auto loadPos = [&](int kt) -> float2 {
    return ((const float2*)pos)[(((b << 1) + g) << 10) + (kt << 6) + lane];
  };

  f32x4 Oacc[2] = {};
  f32x4 lacc = {};

  const int kt0 = half << 3, kt1 = kt0 + 8;
  bf16x8 kN[4], vN[4];
  loadKf(kt0, kN);
  loadVf(kt0, vN);
  float2 pN = loadPos(kt0);

  __syncthreads();   // rpe8 table ready

  for (int kt = kt0; kt < kt1; kt++) {
    bf16x8 kc[4], vc[4];
#pragma unroll
    for (int i2 = 0; i2 < 4; i2++) { kc[i2] = kN[i2]; vc[i2] = vN[i2]; }
    float2 pc = pN;

    // stage wave-private pos for current tile (ys pre-biased by ayc)
    posW[w][lane] = make_float2(fmaf(-15.5f, pc.x, ayc), -15.5f * pc.y);

    if (kt + 1 < kt1) {
      loadKf(kt + 1, kN);
      loadVf(kt + 1, vN);
      pN = loadPos(kt + 1);
    }

#pragma unroll
    for (int jt = 0; jt < 4; jt++) {
      f32x4 z = {};
      f32x4 S = __builtin_amdgcn_mfma_f32_16x16x32_bf16(kc[jt], aq, z, 0, 0, 0);

      // pos pairs for this quad's 4 j's (broadcast reads, conflict-free)
      f32x4 pw01 = *(const f32x4*)&posW[w][(jt << 4) + (quad << 2)];
      f32x4 pw23 = *(const f32x4*)&posW[w][(jt << 4) + (quad << 2) + 2];
      float ysv[4] = {pw01[0], pw01[2], pw23[0], pw23[2]};
      float wyv[4] = {pw01[1], pw01[3], pw23[1], pw23[3]};

      float pv[4];
#pragma unroll
      for (int r = 0; r < 4; r++) {
        float ys = ysv[r];
        float y0f = floorf(ys);
        float fy = ys - y0f;
        int ybase = (int)y0f << 6;
        float sx = axl + wyv[r];
        float x0f = floorf(sx);
        float fx = sx - x0f;
        unsigned u = rpe8[ybase + (int)x0f];
        float g00, g10, g01, g11;
        unpack_fp8_quad(u, g00, g10, g01, g11);
        float h0 = fmaf(fx, g01 - g00, g00);
        float h1 = fmaf(fx, g11 - g10, g10);
        float bias = fmaf(fy, h1 - h0, h0);
        pv[r] = exp2_fast(S[r] + bias);
      }
      // P^T row i=l16, cols j = jt*16 + quad*4 + 0..3: one b64 write
      unsigned p0 = pk2bf(pv[0], pv[1]);
      unsigned p1 = pk2bf(pv[2], pv[3]);
      int wb = (pwrow + (jt << 5) + (quad << 3)) ^ swz;
      *(uint2*)(pw + wb) = make_uint2(p0, p1);
    }

    // ---- P A-frags: lane l16 = i, quad = j-chunk (8 j's each)
    bf16x8 pa0 = *(const bf16x8*)(pw + ((pwrow + (quad << 4)) ^ swz));
    bf16x8 pa1 = *(const bf16x8*)(pw + ((pwrow + 64 + (quad << 4)) ^ swz));

    // ---- PV with current V frags
#pragma unroll
    for (int dt = 0; dt < 2; dt++) {
      Oacc[dt] = __builtin_amdgcn_mfma_f32_16x16x32_bf16(pa0, vc[dt * 2],     Oacc[dt], 0, 0, 0);
      Oacc[dt] = __builtin_amdgcn_mfma_f32_16x16x32_bf16(pa1, vc[dt * 2 + 1], Oacc[dt], 0, 0, 0);
    }
    lacc = __builtin_amdgcn_mfma_f32_16x16x32_bf16(pa0, vones, lacc, 0, 0, 0);
    lacc = __builtin_amdgcn_mfma_f32_16x16x32_bf16(pa1, vones, lacc, 0, 0, 0);
  }

  // ---- combine halves: half-1 partials through LDS (aliased onto Pw)
  f32x4* cbuf = (f32x4*)&Pw[0][0];   // 768 * 16 B = 12 KB <= 16 KB
  __syncthreads();                   // all waves done reading their Pw
  if (half == 1) {
    cbuf[((wv2 * 3 + 0) << 6) + lane] = Oacc[0];
    cbuf[((wv2 * 3 + 1) << 6) + lane] = Oacc[1];
    cbuf[((wv2 * 3 + 2) << 6) + lane] = lacc;
  }
  __syncthreads();
  if (half == 0) {
    f32x4 o0 = cbuf[((wv2 * 3 + 0) << 6) + lane];
    f32x4 o1 = cbuf[((wv2 * 3 + 1) << 6) + lane];
    f32x4 l1 = cbuf[((wv2 * 3 + 2) << 6) + lane];
#pragma unroll
    for (int r = 0; r < 4; r++) {
      Oacc[0][r] += o0[r]; Oacc[1][r] += o1[r]; lacc[r] += l1[r];
    }
    // ---- epilogue -> ao bf16 (rows = i = row0 + quad*4 + r, cols = d)
#pragma unroll
    for (int r = 0; r < 4; r++) {
      float inv = 1.f / lacc[r];
      int row = row0 + (quad << 2) + r;
#pragma unroll
      for (int dt = 0; dt < 2; dt++) {
        ao[(size_t)((b << 10) + row) * 256 + (h << 5) + (dt << 4) + l16] =
            f2bf(Oacc[dt][r] * inv);
      }
    }
  }
}

// ---------------------------------------------------------------------------
extern "C" void kernel_launch(void* const* d_in, const int* in_sizes, int n_in,
                              void* d_out, int out_size, void* d_ws, size_t ws_size,
                              hipStream_t stream) {
  (void)in_sizes; (void)n_in; (void)out_size; (void)ws_size;
  const float* x      = (const float*)d_in[0];
  const float* Wq     = (const float*)d_in[1];
  const float* Wkv    = (const float*)d_in[2];
  const float* conv_w = (const float*)d_in[3];
  const float* conv_b = (const float*)d_in[4];
  const float* ln_g   = (const float*)d_in[5];
  const float* ln_b   = (const float*)d_in[6];
  const float* Woff   = (const float*)d_in[7];
  const float* rpe    = (const float*)d_in[8];
  const float* Wout   = (const float*)d_in[9];
  const float* bout   = (const float*)d_in[10];
  float* out = (float*)d_out;

  float* ws    = (float*)d_ws;
  float* q     = ws;                       // 2,097,152 f32
  float* pos   = ws + 2097152;             //    32,768 f32
  short* kb    = (short*)(ws + 2129920);   // 8192*256 bf16 (K)
  short* vtb   = (short*)(ws + 3178496);   // 256*1024*8 bf16 (V^T [b][d][j])
  short* xsb   = (short*)(ws + 4227072);   // 8192*256 bf16
  short* aob   = (short*)(ws + 5275648);   // 8192*256 bf16
  short* Wkvt  = (short*)(ws + 6324224);   // 512*256 bf16
  short* Woutt = (short*)(ws + 6389760);   // 256*256 bf16
  short* Wqt   = (short*)(ws + 6422528);   // 256*256 bf16

  prep_weights<<<1024, 256, 0, stream>>>(Wkv, Wout, Wq, Wkvt, Woutt, Wqt);
  // 1. q = x @ Wq (bf16 MFMA, f32 A staged+converted, f32 out)
  gemm_bf16<<<dim3(4, 128), 256, 0, stream>>>(nullptr, x, Wqt, q, nullptr, nullptr, 256, nullptr);
  // 2+3. conv + LN + GELU + Woff + tanh -> pos, fused grid_sample -> xs
  conv_pos_sample_kernel<<<4096, 256, 0, stream>>>(q, conv_w, conv_b, ln_g, ln_b,
                                                   Woff, pos, xsb);
  // 4. kv = xs @ Wkv: K -> kb (row-major), V -> vtb (transposed epilogue)
  gemm_bf16<<<dim3(8, 128), 256, 0, stream>>>(xsb, nullptr, Wkvt, nullptr, kb, nullptr, 256, vtb);
  // 5. fused attention v6 (kt-split, 8 waves, 32 waves/CU) -> ao (bf16)
  attn_kernel<<<dim3(16, 8, 8), 512, 0, stream>>>(q, kb, vtb, pos, rpe, aob);
  // 6. out = ao @ Wout + bout (bf16 MFMA, f32 out)
  gemm_bf16<<<dim3(4, 128), 256, 0, stream>>>(aob, nullptr, Woutt, out, nullptr, bout, 256, nullptr);
}

// Round 6
// 262.125 us; speedup vs baseline: 1.6659x; 1.6659x over previous
//
#include <hip/hip_runtime.h>
#include <hip/hip_bf16.h>
#include <hip/hip_fp16.h>
#include <hip/hip_fp8.h>

// DeformableAttention on MI355X.
// prep(weights^T bf16, zero O/l accum) -> gemm_bf16(q) -> fused
// conv+LN+GELU+pos+sample -> gemm_bf16(kv; K->kb, V->vtb transposed) ->
// fused flash-attn v7 (kt split ACROSS BLOCKS: grid 2048, 256-thr blocks,
// ~52 VGPR no cap/spill; 19 KB LDS (36-row rpe window) -> 8 blocks/CU =
// 32 waves/CU; partials combined via f32 atomicAdd, exactly 2 adds/loc,
// deterministic) -> gemm_bf16(out,+bias; A = Oaccum/laccum normalize)

#define EPS_ 1e-5f
#define ASCALE 0.17677669529663687f      // 1/sqrt(32)
#define LOG2E  1.4426950408889634f

typedef __attribute__((ext_vector_type(8))) short bf16x8;
typedef __attribute__((ext_vector_type(4))) float f32x4;

__device__ __forceinline__ short f2bf(float f) {
  union { float f; unsigned u; } v; v.f = f;
  unsigned r = (v.u + 0x7fffu + ((v.u >> 16) & 1u)) >> 16;  // RNE
  return (short)r;
}
__device__ __forceinline__ unsigned pk2bf(float a, float b) {
  union { __hip_bfloat162 h; unsigned u; } v;
  v.h = __float22bfloat162_rn(make_float2(a, b));
  return v.u;
}
__device__ __forceinline__ float exp2_fast(float x) {
  return __builtin_amdgcn_exp2f(x);
}

// fp8 e4m3 quad pack/unpack: HW v_cvt_pk_* on gfx950, sw fallback otherwise.
__device__ __forceinline__ unsigned pack_fp8_quad(float v00, float v10,
                                                  float v01, float v11) {
#if __has_builtin(__builtin_amdgcn_cvt_pk_fp8_f32)
  int r = 0;
  r = __builtin_amdgcn_cvt_pk_fp8_f32(v00, v10, r, false);  // bytes 0,1
  r = __builtin_amdgcn_cvt_pk_fp8_f32(v01, v11, r, true);   // bytes 2,3
  return (unsigned)r;
#else
  __hip_fp8x2_e4m3 elo(make_float2(v00, v10));
  __hip_fp8x2_e4m3 ehi(make_float2(v01, v11));
  return (unsigned)(unsigned short)elo.__x |
         ((unsigned)(unsigned short)ehi.__x << 16);
#endif
}
__device__ __forceinline__ void unpack_fp8_quad(unsigned u, float& g00,
                                                float& g10, float& g01,
                                                float& g11) {
#if __has_builtin(__builtin_amdgcn_cvt_pk_f32_fp8)
  auto ga = __builtin_amdgcn_cvt_pk_f32_fp8((int)u, false);  // (v00, v10)
  auto gb = __builtin_amdgcn_cvt_pk_f32_fp8((int)u, true);   // (v01, v11)
  g00 = ga[0]; g10 = ga[1]; g01 = gb[0]; g11 = gb[1];
#else
  __hip_fp8x2_e4m3 plo, phi;
  plo.__x = (__hip_fp8x2_storage_t)(unsigned short)(u & 0xffffu);
  phi.__x = (__hip_fp8x2_storage_t)(unsigned short)(u >> 16);
  float2 fa = (float2)plo, fb = (float2)phi;
  g00 = fa.x; g10 = fa.y; g01 = fb.x; g11 = fb.y;
#endif
}

// ---------------------------------------------------------------------------
// Weight prep + accumulator zeroing.
// bids [0,1024): Wkvt/Woutt/Wqt transpose+cvt.  bids [1024,3136): zero the
// 8.25 MB Oaccum+laccum region (contiguous) with float4 stores.
// ---------------------------------------------------------------------------
__global__ __launch_bounds__(256) void prep_weights(
    const float* __restrict__ Wkv, const float* __restrict__ Wout,
    const float* __restrict__ Wq, short* __restrict__ Wkvt,
    short* __restrict__ Woutt, short* __restrict__ Wqt,
    float* __restrict__ Oaccum)
{
  int bid = blockIdx.x, k = threadIdx.x;
  if (bid >= 1024) {  // zero Oaccum (2,097,152 f32) + laccum (65,536 f32)
    ((float4*)Oaccum)[(size_t)(bid - 1024) * 256 + k] = make_float4(0.f, 0.f, 0.f, 0.f);
    return;
  }
  if (bid < 512) Wkvt[bid * 256 + k] = f2bf(Wkv[k * 512 + bid]);
  else if (bid < 768) { int n = bid - 512; Woutt[n * 256 + k] = f2bf(Wout[k * 256 + n]); }
  else { int n = bid - 768; Wqt[n * 256 + k] = f2bf(Wq[k * 256 + n]); }
}

// ---------------------------------------------------------------------------
// bf16 MFMA GEMM: C[M,N] = A[M,256] @ Bt[N,256]^T (+bias), with prefetch.
// If vt != null: blocks with n0 >= 256 write V^T to vt[b][d][j].
// If lrow != null (with Af): A[m][k] = Af[m][k] / lrow[m*8 + k/32]
// (attention partial-sum normalization fused into the A load).
// ---------------------------------------------------------------------------
__global__ __launch_bounds__(256) void gemm_bf16(
    const short* __restrict__ Ab, const float* __restrict__ Af,
    const short* __restrict__ Bt,
    float* __restrict__ Cf, short* __restrict__ Cb,
    const float* __restrict__ bias, int N, short* __restrict__ vt,
    const float* __restrict__ lrow)
{
  __shared__ __align__(16) short smem[5120];   // As(2560) | Bs(2560); reused as sV[64][72]
  short* As = smem;
  short* Bs = smem + 2560;
  const int t = threadIdx.x;
  const int n0 = blockIdx.x << 6, m0 = blockIdx.y << 6;
  const int wv = t >> 6, l16 = t & 15, quad = (t & 63) >> 4;
  const int row = t >> 2, koff = (t & 3) << 3;

  auto loadA = [&](int k0) -> bf16x8 {
    if (Af) {
      const float* src = &Af[(size_t)(m0 + row) * 256 + k0 + koff];
      float4 f0 = *(const float4*)src;
      float4 f1 = *(const float4*)(src + 4);
      float s = 1.f;
      if (lrow) s = 1.f / lrow[(size_t)(m0 + row) * 8 + ((k0 + koff) >> 5)];
      union { unsigned u[4]; bf16x8 v; } c;
      c.u[0] = pk2bf(f0.x * s, f0.y * s); c.u[1] = pk2bf(f0.z * s, f0.w * s);
      c.u[2] = pk2bf(f1.x * s, f1.y * s); c.u[3] = pk2bf(f1.z * s, f1.w * s);
      return c.v;
    }
    return *(const bf16x8*)&Ab[(size_t)(m0 + row) * 256 + k0 + koff];
  };

  f32x4 acc[4] = {};
  bf16x8 av = loadA(0);
  bf16x8 bv = *(const bf16x8*)&Bt[(size_t)(n0 + row) * 256 + koff];
  for (int k0 = 0; k0 < 256; k0 += 32) {
    __syncthreads();  // prior-iter frag reads done before overwrite
    *(bf16x8*)&As[row * 40 + koff] = av;
    *(bf16x8*)&Bs[row * 40 + koff] = bv;
    __syncthreads();
    if (k0 + 32 < 256) {  // prefetch next chunk before MFMA section
      av = loadA(k0 + 32);
      bv = *(const bf16x8*)&Bt[(size_t)(n0 + row) * 256 + k0 + 32 + koff];
    }
    bf16x8 a = *(const bf16x8*)&As[((wv << 4) + l16) * 40 + (quad << 3)];
#pragma unroll
    for (int jt = 0; jt < 4; jt++) {
      bf16x8 bb = *(const bf16x8*)&Bs[((jt << 4) + l16) * 40 + (quad << 3)];
      acc[jt] = __builtin_amdgcn_mfma_f32_16x16x32_bf16(a, bb, acc[jt], 0, 0, 0);
    }
  }

  if (vt && n0 >= 256) {
    // ---- V^T epilogue: stage C-tile into LDS as [d][j], store coalesced.
    __syncthreads();                     // done with As/Bs MFMA reads
    short* sV = smem;                    // [64][72] shorts (9216 B <= 10240)
#pragma unroll
    for (int jt = 0; jt < 4; jt++) {
#pragma unroll
      for (int r = 0; r < 4; r++) {
        int nl = (jt << 4) + l16;                 // d-local
        int ml = (wv << 4) + (quad << 2) + r;     // j-local
        sV[nl * 72 + ml] = f2bf(acc[jt][r]);
      }
    }
    __syncthreads();
    int dl = t >> 2, js0 = (t & 3) << 3;
    bf16x8 v0 = *(const bf16x8*)&sV[dl * 72 + js0];
    bf16x8 v1 = *(const bf16x8*)&sV[dl * 72 + js0 + 32];
    int bb = m0 >> 10, j0 = m0 & 1023;
    size_t base = ((size_t)((bb << 8) + (n0 - 256) + dl) << 10) + j0;
    *(bf16x8*)&vt[base + js0]      = v0;
    *(bf16x8*)&vt[base + js0 + 32] = v1;
    return;
  }

#pragma unroll
  for (int jt = 0; jt < 4; jt++) {
#pragma unroll
    for (int r = 0; r < 4; r++) {
      int mrow = m0 + (wv << 4) + (quad << 2) + r;
      int ncol = n0 + (jt << 4) + l16;
      float v = acc[jt][r];
      if (bias) v += bias[ncol];
      if (Cf) Cf[(size_t)mrow * N + ncol] = v;
      else    Cb[(size_t)mrow * N + ncol] = f2bf(v);
    }
  }
}

// ---------------------------------------------------------------------------
// Fused: conv5x5 depthwise + LN(128) + GELU + @Woff + tanh -> pos, then
// grid_sample of this pixel's group channels -> xs (bf16). Wave per (b,g,pix).
// ---------------------------------------------------------------------------
__global__ __launch_bounds__(256) void conv_pos_sample_kernel(
    const float* __restrict__ q, const float* __restrict__ conv_w,
    const float* __restrict__ conv_b, const float* __restrict__ ln_g,
    const float* __restrict__ ln_b, const float* __restrict__ Woff,
    float* __restrict__ pos, short* __restrict__ xsb)
{
  const int p = (blockIdx.x << 2) + (threadIdx.x >> 6);
  const int lane = threadIdx.x & 63;
  const int bg = p >> 10, pix = p & 1023;
  const int hh = pix >> 5, ww = pix & 31;
  const int b = bg >> 1, g = bg & 1;
  const int c0 = lane << 1;

  float2 cb = *(const float2*)&conv_b[c0];
  float a0 = cb.x, a1 = cb.y;
  const float* w0 = conv_w + c0 * 25;
  const float* w1 = w0 + 25;
#pragma unroll
  for (int dy = 0; dy < 5; dy++) {
    int y = hh + dy - 2;
    if ((unsigned)y < 32u) {
#pragma unroll
      for (int dx = 0; dx < 5; dx++) {
        int x = ww + dx - 2;
        if ((unsigned)x < 32u) {
          float2 qv = *(const float2*)&q[(size_t)((b << 10) + (y << 5) + x) * 256 + (g << 7) + c0];
          a0 = fmaf(qv.x, w0[dy * 5 + dx], a0);
          a1 = fmaf(qv.y, w1[dy * 5 + dx], a1);
        }
      }
    }
  }
  float s1 = a0 + a1, s2 = a0 * a0 + a1 * a1;
#pragma unroll
  for (int o = 32; o; o >>= 1) { s1 += __shfl_xor(s1, o); s2 += __shfl_xor(s2, o); }
  float mu = s1 * (1.f / 128.f);
  float inv = rsqrtf(fmaf(-mu, mu, s2 * (1.f / 128.f)) + EPS_);
  float2 lg = *(const float2*)&ln_g[c0];
  float2 lb = *(const float2*)&ln_b[c0];
  float v0 = (a0 - mu) * inv * lg.x + lb.x;
  float v1 = (a1 - mu) * inv * lg.y + lb.y;
  float ge0 = 0.5f * v0 * (1.f + erff(v0 * 0.70710678118654752f));
  float ge1 = 0.5f * v1 * (1.f + erff(v1 * 0.70710678118654752f));
  float2 W0 = *(const float2*)&Woff[c0 * 2];
  float2 W1 = *(const float2*)&Woff[c0 * 2 + 2];
  float o0 = ge0 * W0.x + ge1 * W1.x;
  float o1 = ge0 * W0.y + ge1 * W1.y;
#pragma unroll
  for (int o = 32; o; o >>= 1) { o0 += __shfl_xor(o0, o); o1 += __shfl_xor(o1, o); }
  float py = tanhf(o0) * 0.0625f + ((hh + 0.5f) * 0.0625f - 1.f);
  float px = tanhf(o1) * 0.0625f + ((ww + 0.5f) * 0.0625f - 1.f);
  if (lane == 0)
    ((float2*)pos)[(bg << 10) + pix] = make_float2(py, px);

  float x = (px + 1.f) * 15.5f;
  float y = (py + 1.f) * 15.5f;
  float x0f = floorf(x), y0f = floorf(y);
  int ix0 = (int)x0f, iy0 = (int)y0f;
  float fx = x - x0f, fy = y - y0f;
  float ac0 = 0.f, ac1 = 0.f;
#pragma unroll
  for (int dy = 0; dy < 2; dy++) {
#pragma unroll
    for (int dx = 0; dx < 2; dx++) {
      int yi = iy0 + dy, xi = ix0 + dx;
      float w = (dy ? fy : 1.f - fy) * (dx ? fx : 1.f - fx);
      if ((unsigned)yi < 32u && (unsigned)xi < 32u) {
        float2 qv = *(const float2*)&q[(size_t)((b << 10) + (yi << 5) + xi) * 256 + (g << 7) + c0];
        ac0 = fmaf(w, qv.x, ac0);
        ac1 = fmaf(w, qv.y, ac1);
      }
    }
  }
  *(unsigned*)&xsb[(size_t)((b << 10) + pix) * 256 + (g << 7) + c0] = pk2bf(ac0, ac1);
}

// ---------------------------------------------------------------------------
// Fused attention v7: kt split ACROSS BLOCKS.  Grid dim3(32,8,8):
// it = bx>>1, half = bx&1 -> kt in [half*8, half*8+8) over the same 64 rows.
// 256-thread blocks (proven ~52 VGPR body, cap 64 via (256,8): no spill) ->
// 8 blocks/CU via 19 KB LDS (rpe table shrunk to a 36-row window: ys spans
// ayc +/- 16 only) = 32 waves/CU.  Partial (Oacc, lacc) atomicAdd'd to f32
// accumulators (exactly 2 adds/location, commutative -> deterministic);
// out-GEMM normalizes.  Swapped QK^T, wave-local P, zero kt-loop barriers.
// ---------------------------------------------------------------------------
__global__ __launch_bounds__(256, 8) void attn_kernel(
    const float* __restrict__ q, const short* __restrict__ kb,
    const short* __restrict__ vtb, const float* __restrict__ pos,
    const float* __restrict__ rpe, float* __restrict__ Oaccum,
    float* __restrict__ laccum)
{
  const int it = blockIdx.x >> 1, half = blockIdx.x & 1;
  const int h = blockIdx.y, b = blockIdx.z;
  const int g = h >> 2, t = threadIdx.x;
  const int w = t >> 6, l16 = t & 15, quad = (t & 63) >> 4;
  const int lane = t & 63;

  __shared__ __align__(16) unsigned rpe8[36 * 64];  // 9 KB fp8 quad window
  __shared__ __align__(16) short Pw[4][1024];       // 8 KB wave-private P[16][64]
  __shared__ __align__(16) float2 posW[4][64];      // 2 KB wave-private pos

  // ---- block-uniform y-window: ys = ayc - 15.5*py, ayc(hh0=2it) minimal.
  const float aycb = 15.5f * ((2 * it + 0.5f) * 0.0625f - 1.f) + 31.f;
  int ylo = (int)floorf(aycb) - 16;
  ylo = ylo < 0 ? 0 : (ylo > 28 ? 28 : ylo);

  // ---- stage fp8 rpe quad table over the 36-row window (origin +31).
  {
    const float* rp = rpe + h * 3969;
    for (int i = t; i < 36 * 64; i += 256) {
      int ty = ylo + (i >> 6), tx = i & 63;
      float v00 = 0.f, v10 = 0.f, v01 = 0.f, v11 = 0.f;
      if (tx <= 62) {
        if (ty <= 62) v00 = rp[ty * 63 + tx] * LOG2E;
        if (ty <= 61) v10 = rp[(ty + 1) * 63 + tx] * LOG2E;
      }
      if (tx <= 61) {
        if (ty <= 62) v01 = rp[ty * 63 + tx + 1] * LOG2E;
        if (ty <= 61) v11 = rp[(ty + 1) * 63 + tx + 1] * LOG2E;
      }
      rpe8[i] = pack_fp8_quad(v00, v10, v01, v11);
    }
  }

  // ---- Q B-frag from global (once), scaled by ASCALE*LOG2E.
  const int row0 = (it << 6) + (w << 4);
  bf16x8 aq;
  {
    const float* src = q + (size_t)((b << 10) + row0 + l16) * 256 + (h << 5) + (quad << 3);
    float4 f0 = *(const float4*)src;
    float4 f1 = *(const float4*)(src + 4);
    const float sc = ASCALE * LOG2E;
    union { unsigned u[4]; bf16x8 v; } c;
    c.u[0] = pk2bf(f0.x * sc, f0.y * sc); c.u[1] = pk2bf(f0.z * sc, f0.w * sc);
    c.u[2] = pk2bf(f1.x * sc, f1.y * sc); c.u[3] = pk2bf(f1.z * sc, f1.w * sc);
    aq = c.v;
  }

  // sampling coords (origin +31): wave raster row hh = 2it + (w>>1)
  const float ayc = 15.5f * (((row0 >> 5) + 0.5f) * 0.0625f - 1.f) + 31.f;
  const int ww_i = ((w & 1) << 4) + l16;
  const float axl = 15.5f * ((ww_i + 0.5f) * 0.0625f - 1.f) + 31.f;

  bf16x8 vones;
#pragma unroll
  for (int i = 0; i < 8; i++) vones[i] = (short)0x3F80;  // bf16 1.0

  // wave-private P buffer, XOR-swizzled rows (row stride 128 B)
  char* pw = (char*)&Pw[w][0];
  const int pwrow = l16 << 7;
  const int swz = (l16 & 7) << 4;

  f32x4 Oacc[2] = {};
  f32x4 lacc = {};

  const int kt0 = half << 3, kt1 = kt0 + 8;

  __syncthreads();   // rpe8 table ready — the ONLY block-wide barrier

  for (int kt = kt0; kt < kt1; kt++) {
    const int jb = kt << 6;

    // ---- stage wave-private pos: lane j -> (ayc - 15.5*py, -15.5*px)
    {
      float2 pp = ((const float2*)pos)[(((b << 1) + g) << 10) + jb + lane];
      posW[w][lane] = make_float2(fmaf(-15.5f, pp.x, ayc), -15.5f * pp.y);
    }

#pragma unroll
    for (int jt = 0; jt < 4; jt++) {
      // K A-frag straight from global: A[row=j][k=d]
      bf16x8 ak = *(const bf16x8*)&kb[(size_t)((b << 10) + jb + (jt << 4) + l16) * 256 + (h << 5) + (quad << 3)];
      f32x4 z = {};
      f32x4 S = __builtin_amdgcn_mfma_f32_16x16x32_bf16(ak, aq, z, 0, 0, 0);

      // pos pairs for this quad's 4 j's (broadcast reads, conflict-free)
      f32x4 pw01 = *(const f32x4*)&posW[w][(jt << 4) + (quad << 2)];
      f32x4 pw23 = *(const f32x4*)&posW[w][(jt << 4) + (quad << 2) + 2];
      float ysv[4] = {pw01[0], pw01[2], pw23[0], pw23[2]};
      float wyv[4] = {pw01[1], pw01[3], pw23[1], pw23[3]};

      float pv[4];
#pragma unroll
      for (int r = 0; r < 4; r++) {
        float ys = ysv[r];
        float y0f = floorf(ys);
        float fy = ys - y0f;
        int ybase = ((int)y0f - ylo) << 6;
        float sx = axl + wyv[r];
        float x0f = floorf(sx);
        float fx = sx - x0f;
        unsigned u = rpe8[ybase + (int)x0f];
        float g00, g10, g01, g11;
        unpack_fp8_quad(u, g00, g10, g01, g11);
        float h0 = fmaf(fx, g01 - g00, g00);
        float h1 = fmaf(fx, g11 - g10, g10);
        float bias = fmaf(fy, h1 - h0, h0);
        pv[r] = exp2_fast(S[r] + bias);
      }
      // P^T row i=l16, cols j = jt*16 + quad*4 + 0..3: one b64 write
      unsigned p0 = pk2bf(pv[0], pv[1]);
      unsigned p1 = pk2bf(pv[2], pv[3]);
      int wb = (pwrow + (jt << 5) + (quad << 3)) ^ swz;
      *(uint2*)(pw + wb) = make_uint2(p0, p1);
    }

    // ---- P A-frags: lane l16 = i, quad = j-chunk (8 j's each)
    bf16x8 pa0 = *(const bf16x8*)(pw + ((pwrow + (quad << 4)) ^ swz));
    bf16x8 pa1 = *(const bf16x8*)(pw + ((pwrow + 64 + (quad << 4)) ^ swz));

    // ---- PV: V B-frags from global vtb[b][d][j] (contiguous j)
#pragma unroll
    for (int dt = 0; dt < 2; dt++) {
      const short* vb = &vtb[((size_t)((b << 8) + (h << 5) + (dt << 4) + l16) << 10) + jb + (quad << 3)];
      bf16x8 vb0 = *(const bf16x8*)vb;          // j-half 0
      bf16x8 vb1 = *(const bf16x8*)(vb + 32);   // j-half 1
      Oacc[dt] = __builtin_amdgcn_mfma_f32_16x16x32_bf16(pa0, vb0, Oacc[dt], 0, 0, 0);
      Oacc[dt] = __builtin_amdgcn_mfma_f32_16x16x32_bf16(pa1, vb1, Oacc[dt], 0, 0, 0);
    }
    lacc = __builtin_amdgcn_mfma_f32_16x16x32_bf16(pa0, vones, lacc, 0, 0, 0);
    lacc = __builtin_amdgcn_mfma_f32_16x16x32_bf16(pa1, vones, lacc, 0, 0, 0);
  }

  // ---- partial accumulation: exactly 2 atomic adds per location (det.)
#pragma unroll
  for (int r = 0; r < 4; r++) {
    int row = row0 + (quad << 2) + r;
    size_t mb = (size_t)((b << 10) + row);
#pragma unroll
    for (int dt = 0; dt < 2; dt++)
      atomicAdd(&Oaccum[mb * 256 + (h << 5) + (dt << 4) + l16], Oacc[dt][r]);
    if (l16 == 0)
      atomicAdd(&laccum[mb * 8 + h], lacc[r]);
  }
}

// ---------------------------------------------------------------------------
extern "C" void kernel_launch(void* const* d_in, const int* in_sizes, int n_in,
                              void* d_out, int out_size, void* d_ws, size_t ws_size,
                              hipStream_t stream) {
  (void)in_sizes; (void)n_in; (void)out_size; (void)ws_size;
  const float* x      = (const float*)d_in[0];
  const float* Wq     = (const float*)d_in[1];
  const float* Wkv    = (const float*)d_in[2];
  const float* conv_w = (const float*)d_in[3];
  const float* conv_b = (const float*)d_in[4];
  const float* ln_g   = (const float*)d_in[5];
  const float* ln_b   = (const float*)d_in[6];
  const float* Woff   = (const float*)d_in[7];
  const float* rpe    = (const float*)d_in[8];
  const float* Wout   = (const float*)d_in[9];
  const float* bout   = (const float*)d_in[10];
  float* out = (float*)d_out;

  float* ws     = (float*)d_ws;
  float* q      = ws;                       // 2,097,152 f32
  float* pos    = ws + 2097152;             //    32,768 f32
  short* kb     = (short*)(ws + 2129920);   // 8192*256 bf16 (K)       -> 1,048,576 f32
  short* vtb    = (short*)(ws + 3178496);   // 8*256*1024 bf16 (V^T)   -> 1,048,576 f32
  short* xsb    = (short*)(ws + 4227072);   // 8192*256 bf16           -> 1,048,576 f32
  short* Wkvt   = (short*)(ws + 5275648);   // 512*256 bf16            ->    65,536 f32
  short* Woutt  = (short*)(ws + 5341184);   // 256*256 bf16            ->    32,768 f32
  short* Wqt    = (short*)(ws + 5373952);   // 256*256 bf16            ->    32,768 f32
  float* Oaccum = ws + 5406720;             // 8192*256 f32 = 2,097,152
  float* laccum = ws + 7503872;             // 8192*8 f32   =    65,536
  // total ~28.9 MB

  // prep: 1024 transpose blocks + 2112 zeroing blocks (Oaccum+laccum)
  prep_weights<<<3136, 256, 0, stream>>>(Wkv, Wout, Wq, Wkvt, Woutt, Wqt, Oaccum);
  // 1. q = x @ Wq (bf16 MFMA, f32 A staged+converted, f32 out)
  gemm_bf16<<<dim3(4, 128), 256, 0, stream>>>(nullptr, x, Wqt, q, nullptr, nullptr, 256, nullptr, nullptr);
  // 2+3. conv + LN + GELU + Woff + tanh -> pos, fused grid_sample -> xs
  conv_pos_sample_kernel<<<4096, 256, 0, stream>>>(q, conv_w, conv_b, ln_g, ln_b,
                                                   Woff, pos, xsb);
  // 4. kv = xs @ Wkv: K -> kb (row-major), V -> vtb (transposed epilogue)
  gemm_bf16<<<dim3(8, 128), 256, 0, stream>>>(xsb, nullptr, Wkvt, nullptr, kb, nullptr, 256, vtb, nullptr);
  // 5. fused attention v7 (block-level kt split, 32 waves/CU) -> Oaccum/laccum
  attn_kernel<<<dim3(32, 8, 8), 256, 0, stream>>>(q, kb, vtb, pos, rpe, Oaccum, laccum);
  // 6. out = (Oaccum/laccum) @ Wout + bout (normalize fused into A-load)
  gemm_bf16<<<dim3(4, 128), 256, 0, stream>>>(nullptr, Oaccum, Woutt, out, nullptr, bout, 256, nullptr, laccum);
}

// Round 7
// 249.996 us; speedup vs baseline: 1.7468x; 1.0485x over previous
//
#include <hip/hip_runtime.h>
#include <hip/hip_bf16.h>
#include <hip/hip_fp16.h>
#include <hip/hip_fp8.h>

// DeformableAttention on MI355X.
// prep(weights^T bf16) -> gemm_bf16(q) -> fused conv+LN+GELU+pos+sample ->
// gemm_bf16(kv; K->kb, V->vtb transposed) -> fused flash-attn v8
// (posAll staged ONCE; all-16 rpe gathers batched before any P write ->
// co-outstanding ds_reads; K/V loads issued early; 128-VGPR budget)
// -> gemm_bf16(out,+bias)

#define EPS_ 1e-5f
#define ASCALE 0.17677669529663687f      // 1/sqrt(32)
#define LOG2E  1.4426950408889634f

typedef __attribute__((ext_vector_type(8))) short bf16x8;
typedef __attribute__((ext_vector_type(4))) float f32x4;

__device__ __forceinline__ short f2bf(float f) {
  union { float f; unsigned u; } v; v.f = f;
  unsigned r = (v.u + 0x7fffu + ((v.u >> 16) & 1u)) >> 16;  // RNE
  return (short)r;
}
__device__ __forceinline__ unsigned pk2bf(float a, float b) {
  union { __hip_bfloat162 h; unsigned u; } v;
  v.h = __float22bfloat162_rn(make_float2(a, b));
  return v.u;
}
__device__ __forceinline__ float exp2_fast(float x) {
  return __builtin_amdgcn_exp2f(x);
}

// fp8 e4m3 quad pack/unpack: HW v_cvt_pk_* on gfx950, sw fallback otherwise.
__device__ __forceinline__ unsigned pack_fp8_quad(float v00, float v10,
                                                  float v01, float v11) {
#if __has_builtin(__builtin_amdgcn_cvt_pk_fp8_f32)
  int r = 0;
  r = __builtin_amdgcn_cvt_pk_fp8_f32(v00, v10, r, false);  // bytes 0,1
  r = __builtin_amdgcn_cvt_pk_fp8_f32(v01, v11, r, true);   // bytes 2,3
  return (unsigned)r;
#else
  __hip_fp8x2_e4m3 elo(make_float2(v00, v10));
  __hip_fp8x2_e4m3 ehi(make_float2(v01, v11));
  return (unsigned)(unsigned short)elo.__x |
         ((unsigned)(unsigned short)ehi.__x << 16);
#endif
}
__device__ __forceinline__ void unpack_fp8_quad(unsigned u, float& g00,
                                                float& g10, float& g01,
                                                float& g11) {
#if __has_builtin(__builtin_amdgcn_cvt_pk_f32_fp8)
  auto ga = __builtin_amdgcn_cvt_pk_f32_fp8((int)u, false);  // (v00, v10)
  auto gb = __builtin_amdgcn_cvt_pk_f32_fp8((int)u, true);   // (v01, v11)
  g00 = ga[0]; g10 = ga[1]; g01 = gb[0]; g11 = gb[1];
#else
  __hip_fp8x2_e4m3 plo, phi;
  plo.__x = (__hip_fp8x2_storage_t)(unsigned short)(u & 0xffffu);
  phi.__x = (__hip_fp8x2_storage_t)(unsigned short)(u >> 16);
  float2 fa = (float2)plo, fb = (float2)phi;
  g00 = fa.x; g10 = fa.y; g01 = fb.x; g11 = fb.y;
#endif
}

// ---------------------------------------------------------------------------
// Weight prep: Wkvt[n][k]=bf16(Wkv[k][n]); Woutt, Wqt likewise.
// ---------------------------------------------------------------------------
__global__ __launch_bounds__(256) void prep_weights(
    const float* __restrict__ Wkv, const float* __restrict__ Wout,
    const float* __restrict__ Wq, short* __restrict__ Wkvt,
    short* __restrict__ Woutt, short* __restrict__ Wqt)
{
  int bid = blockIdx.x, k = threadIdx.x;
  if (bid < 512) Wkvt[bid * 256 + k] = f2bf(Wkv[k * 512 + bid]);
  else if (bid < 768) { int n = bid - 512; Woutt[n * 256 + k] = f2bf(Wout[k * 256 + n]); }
  else { int n = bid - 768; Wqt[n * 256 + k] = f2bf(Wq[k * 256 + n]); }
}

// ---------------------------------------------------------------------------
// bf16 MFMA GEMM: C[M,N] = A[M,256] @ Bt[N,256]^T (+bias), with prefetch.
// If vt != null: blocks with n0 >= 256 write V^T to vt[b][d][j] (bf16)
// via an LDS transpose (coalesced b128 stores), and skip the normal C write.
// ---------------------------------------------------------------------------
__global__ __launch_bounds__(256) void gemm_bf16(
    const short* __restrict__ Ab, const float* __restrict__ Af,
    const short* __restrict__ Bt,
    float* __restrict__ Cf, short* __restrict__ Cb,
    const float* __restrict__ bias, int N, short* __restrict__ vt)
{
  __shared__ __align__(16) short smem[5120];   // As(2560) | Bs(2560); reused as sV[64][72]
  short* As = smem;
  short* Bs = smem + 2560;
  const int t = threadIdx.x;
  const int n0 = blockIdx.x << 6, m0 = blockIdx.y << 6;
  const int wv = t >> 6, l16 = t & 15, quad = (t & 63) >> 4;
  const int row = t >> 2, koff = (t & 3) << 3;

  auto loadA = [&](int k0) -> bf16x8 {
    if (Af) {
      const float* src = &Af[(size_t)(m0 + row) * 256 + k0 + koff];
      float4 f0 = *(const float4*)src;
      float4 f1 = *(const float4*)(src + 4);
      union { unsigned u[4]; bf16x8 v; } c;
      c.u[0] = pk2bf(f0.x, f0.y); c.u[1] = pk2bf(f0.z, f0.w);
      c.u[2] = pk2bf(f1.x, f1.y); c.u[3] = pk2bf(f1.z, f1.w);
      return c.v;
    }
    return *(const bf16x8*)&Ab[(size_t)(m0 + row) * 256 + k0 + koff];
  };

  f32x4 acc[4] = {};
  bf16x8 av = loadA(0);
  bf16x8 bv = *(const bf16x8*)&Bt[(size_t)(n0 + row) * 256 + koff];
  for (int k0 = 0; k0 < 256; k0 += 32) {
    __syncthreads();  // prior-iter frag reads done before overwrite
    *(bf16x8*)&As[row * 40 + koff] = av;
    *(bf16x8*)&Bs[row * 40 + koff] = bv;
    __syncthreads();
    if (k0 + 32 < 256) {  // prefetch next chunk before MFMA section
      av = loadA(k0 + 32);
      bv = *(const bf16x8*)&Bt[(size_t)(n0 + row) * 256 + k0 + 32 + koff];
    }
    bf16x8 a = *(const bf16x8*)&As[((wv << 4) + l16) * 40 + (quad << 3)];
#pragma unroll
    for (int jt = 0; jt < 4; jt++) {
      bf16x8 bb = *(const bf16x8*)&Bs[((jt << 4) + l16) * 40 + (quad << 3)];
      acc[jt] = __builtin_amdgcn_mfma_f32_16x16x32_bf16(a, bb, acc[jt], 0, 0, 0);
    }
  }

  if (vt && n0 >= 256) {
    // ---- V^T epilogue: stage C-tile into LDS as [d][j], store coalesced.
    __syncthreads();                     // done with As/Bs MFMA reads
    short* sV = smem;                    // [64][72] shorts (9216 B <= 10240)
#pragma unroll
    for (int jt = 0; jt < 4; jt++) {
#pragma unroll
      for (int r = 0; r < 4; r++) {
        int nl = (jt << 4) + l16;                 // d-local
        int ml = (wv << 4) + (quad << 2) + r;     // j-local
        sV[nl * 72 + ml] = f2bf(acc[jt][r]);
      }
    }
    __syncthreads();
    int dl = t >> 2, js0 = (t & 3) << 3;
    bf16x8 v0 = *(const bf16x8*)&sV[dl * 72 + js0];
    bf16x8 v1 = *(const bf16x8*)&sV[dl * 72 + js0 + 32];
    int bb = m0 >> 10, j0 = m0 & 1023;
    size_t base = ((size_t)((bb << 8) + (n0 - 256) + dl) << 10) + j0;
    *(bf16x8*)&vt[base + js0]      = v0;
    *(bf16x8*)&vt[base + js0 + 32] = v1;
    return;
  }

#pragma unroll
  for (int jt = 0; jt < 4; jt++) {
#pragma unroll
    for (int r = 0; r < 4; r++) {
      int mrow = m0 + (wv << 4) + (quad << 2) + r;
      int ncol = n0 + (jt << 4) + l16;
      float v = acc[jt][r];
      if (bias) v += bias[ncol];
      if (Cf) Cf[(size_t)mrow * N + ncol] = v;
      else    Cb[(size_t)mrow * N + ncol] = f2bf(v);
    }
  }
}

// ---------------------------------------------------------------------------
// Fused: conv5x5 depthwise + LN(128) + GELU + @Woff + tanh -> pos, then
// grid_sample of this pixel's group channels -> xs (bf16). Wave per (b,g,pix).
// ---------------------------------------------------------------------------
__global__ __launch_bounds__(256) void conv_pos_sample_kernel(
    const float* __restrict__ q, const float* __restrict__ conv_w,
    const float* __restrict__ conv_b, const float* __restrict__ ln_g,
    const float* __restrict__ ln_b, const float* __restrict__ Woff,
    float* __restrict__ pos, short* __restrict__ xsb)
{
  const int p = (blockIdx.x << 2) + (threadIdx.x >> 6);
  const int lane = threadIdx.x & 63;
  const int bg = p >> 10, pix = p & 1023;
  const int hh = pix >> 5, ww = pix & 31;
  const int b = bg >> 1, g = bg & 1;
  const int c0 = lane << 1;

  float2 cb = *(const float2*)&conv_b[c0];
  float a0 = cb.x, a1 = cb.y;
  const float* w0 = conv_w + c0 * 25;
  const float* w1 = w0 + 25;
#pragma unroll
  for (int dy = 0; dy < 5; dy++) {
    int y = hh + dy - 2;
    if ((unsigned)y < 32u) {
#pragma unroll
      for (int dx = 0; dx < 5; dx++) {
        int x = ww + dx - 2;
        if ((unsigned)x < 32u) {
          float2 qv = *(const float2*)&q[(size_t)((b << 10) + (y << 5) + x) * 256 + (g << 7) + c0];
          a0 = fmaf(qv.x, w0[dy * 5 + dx], a0);
          a1 = fmaf(qv.y, w1[dy * 5 + dx], a1);
        }
      }
    }
  }
  float s1 = a0 + a1, s2 = a0 * a0 + a1 * a1;
#pragma unroll
  for (int o = 32; o; o >>= 1) { s1 += __shfl_xor(s1, o); s2 += __shfl_xor(s2, o); }
  float mu = s1 * (1.f / 128.f);
  float inv = rsqrtf(fmaf(-mu, mu, s2 * (1.f / 128.f)) + EPS_);
  float2 lg = *(const float2*)&ln_g[c0];
  float2 lb = *(const float2*)&ln_b[c0];
  float v0 = (a0 - mu) * inv * lg.x + lb.x;
  float v1 = (a1 - mu) * inv * lg.y + lb.y;
  float ge0 = 0.5f * v0 * (1.f + erff(v0 * 0.70710678118654752f));
  float ge1 = 0.5f * v1 * (1.f + erff(v1 * 0.70710678118654752f));
  float2 W0 = *(const float2*)&Woff[c0 * 2];
  float2 W1 = *(const float2*)&Woff[c0 * 2 + 2];
  float o0 = ge0 * W0.x + ge1 * W1.x;
  float o1 = ge0 * W0.y + ge1 * W1.y;
#pragma unroll
  for (int o = 32; o; o >>= 1) { o0 += __shfl_xor(o0, o); o1 += __shfl_xor(o1, o); }
  float py = tanhf(o0) * 0.0625f + ((hh + 0.5f) * 0.0625f - 1.f);
  float px = tanhf(o1) * 0.0625f + ((ww + 0.5f) * 0.0625f - 1.f);
  if (lane == 0)
    ((float2*)pos)[(bg << 10) + pix] = make_float2(py, px);

  float x = (px + 1.f) * 15.5f;
  float y = (py + 1.f) * 15.5f;
  float x0f = floorf(x), y0f = floorf(y);
  int ix0 = (int)x0f, iy0 = (int)y0f;
  float fx = x - x0f, fy = y - y0f;
  float ac0 = 0.f, ac1 = 0.f;
#pragma unroll
  for (int dy = 0; dy < 2; dy++) {
#pragma unroll
    for (int dx = 0; dx < 2; dx++) {
      int yi = iy0 + dy, xi = ix0 + dx;
      float w = (dy ? fy : 1.f - fy) * (dx ? fx : 1.f - fx);
      if ((unsigned)yi < 32u && (unsigned)xi < 32u) {
        float2 qv = *(const float2*)&q[(size_t)((b << 10) + (yi << 5) + xi) * 256 + (g << 7) + c0];
        ac0 = fmaf(w, qv.x, ac0);
        ac1 = fmaf(w, qv.y, ac1);
      }
    }
  }
  *(unsigned*)&xsb[(size_t)((b << 10) + pix) * 256 + (g << 7) + c0] = pk2bf(ac0, ac1);
}

// ---------------------------------------------------------------------------
// Fused attention v8: one block = (64-row i-tile, head, batch), grid 1024,
// 256 threads, __launch_bounds__(256,4) -> 128-VGPR budget.
// Key change vs v5: the per-kt DS dependence chain is broken.
//  - posAll[1024] staged ONCE before the loop (read-only in-loop).
//  - ALL 16 rpe8 gather addresses computed and ALL 16 ds_read_b32 issued
//    in one batch BEFORE any P write -> gathers co-outstanding (latency
//    amortized) instead of serialized behind XOR-swizzled P writes.
//  - K/V global loads issued at the top of the body, consumed mid/late.
// Swapped QK^T, wave-local vectorized P, zero barriers in the kt loop.
// LDS 32.8 KB -> 4 blocks/CU (grid-limited anyway).
// ---------------------------------------------------------------------------
__global__ __launch_bounds__(256, 4) void attn_kernel(
    const float* __restrict__ q, const short* __restrict__ kb,
    const short* __restrict__ vtb, const float* __restrict__ pos,
    const float* __restrict__ rpe, short* __restrict__ ao)
{
  const int it = blockIdx.x, h = blockIdx.y, b = blockIdx.z;
  const int g = h >> 2, t = threadIdx.x;
  const int wv = t >> 6, l16 = t & 15, quad = (t & 63) >> 4;

  __shared__ __align__(16) unsigned rpe8[64 * 64];  // 16 KB fp8 quad table
  __shared__ __align__(16) float2 posAll[1024];     // 8 KB all-j pos (staged once)
  __shared__ __align__(16) short Pw[4][1024];       // 8 KB wave-private P[16][64]

  // ---- stage fp8 rpe quad table over the reachable window (origin +31).
  {
    const float* rp = rpe + h * 3969;
    for (int i = t; i < 4096; i += 256) {
      int ty = i >> 6, tx = i & 63;
      float v00 = 0.f, v10 = 0.f, v01 = 0.f, v11 = 0.f;
      if (tx <= 62) {
        if (ty <= 62) v00 = rp[ty * 63 + tx] * LOG2E;
        if (ty <= 61) v10 = rp[(ty + 1) * 63 + tx] * LOG2E;
      }
      if (tx <= 61) {
        if (ty <= 62) v01 = rp[ty * 63 + tx + 1] * LOG2E;
        if (ty <= 61) v11 = rp[(ty + 1) * 63 + tx + 1] * LOG2E;
      }
      rpe8[i] = pack_fp8_quad(v00, v10, v01, v11);
    }
  }
  // ---- stage ALL pos for this (b,g) once: posAll[j] = (-15.5py, -15.5px)
  {
    const float2* pp = (const float2*)pos + (((b << 1) + g) << 10);
    for (int i = t; i < 1024; i += 256) {
      float2 v = pp[i];
      posAll[i] = make_float2(-15.5f * v.x, -15.5f * v.y);
    }
  }

  // ---- Q B-frag from global (once), scaled by ASCALE*LOG2E.
  const int row0 = (it << 6) + (wv << 4);
  bf16x8 aq;
  {
    const float* src = q + (size_t)((b << 10) + row0 + l16) * 256 + (h << 5) + (quad << 3);
    float4 f0 = *(const float4*)src;
    float4 f1 = *(const float4*)(src + 4);
    const float sc = ASCALE * LOG2E;
    union { unsigned u[4]; bf16x8 v; } c;
    c.u[0] = pk2bf(f0.x * sc, f0.y * sc); c.u[1] = pk2bf(f0.z * sc, f0.w * sc);
    c.u[2] = pk2bf(f1.x * sc, f1.y * sc); c.u[3] = pk2bf(f1.z * sc, f1.w * sc);
    aq = c.v;
  }

  // sampling coords (origin +31): i = row0 + l16; hh = row0>>5 wave-uniform
  const float ayc = 15.5f * (((row0 >> 5) + 0.5f) * 0.0625f - 1.f) + 31.f;
  const int ww_i = ((wv & 1) << 4) + l16;
  const float axl = 15.5f * ((ww_i + 0.5f) * 0.0625f - 1.f) + 31.f;

  bf16x8 vones;
#pragma unroll
  for (int i = 0; i < 8; i++) vones[i] = (short)0x3F80;  // bf16 1.0

  // wave-private P buffer, XOR-swizzled rows (row stride 128 B)
  char* pw = (char*)&Pw[wv][0];
  const int pwrow = l16 << 7;
  const int swz = (l16 & 7) << 4;

  f32x4 Oacc[2] = {};
  f32x4 lacc = {};

  __syncthreads();   // rpe8 + posAll ready — the ONLY block-wide barrier

  for (int kt = 0; kt < 16; kt++) {
    const int jb = kt << 6;

    // ---- issue this kt's V and K global loads first (consumed mid/late)
    bf16x8 vc[4];
#pragma unroll
    for (int dt = 0; dt < 2; dt++) {
      const short* vb = &vtb[((size_t)((b << 8) + (h << 5) + (dt << 4) + l16) << 10) + jb + (quad << 3)];
      vc[dt * 2]     = *(const bf16x8*)vb;          // j-half 0
      vc[dt * 2 + 1] = *(const bf16x8*)(vb + 32);   // j-half 1
    }
    bf16x8 kc[4];
#pragma unroll
    for (int jt = 0; jt < 4; jt++)
      kc[jt] = *(const bf16x8*)&kb[(size_t)((b << 10) + jb + (jt << 4) + l16) * 256 + (h << 5) + (quad << 3)];

    // ---- gather phase: ALL 16 addresses + ALL 16 ds_read_b32, batched
    float fxv[16], fyv[16];
    unsigned uv[16];
#pragma unroll
    for (int jt = 0; jt < 4; jt++) {
      f32x4 p01 = *(const f32x4*)&posAll[jb + (jt << 4) + (quad << 2)];
      f32x4 p23 = *(const f32x4*)&posAll[jb + (jt << 4) + (quad << 2) + 2];
      float ysv[4] = {ayc + p01[0], ayc + p01[2], ayc + p23[0], ayc + p23[2]};
      float wxv[4] = {p01[1], p01[3], p23[1], p23[3]};
#pragma unroll
      for (int r = 0; r < 4; r++) {
        int s = (jt << 2) + r;
        float ys = ysv[r];
        float y0f = floorf(ys);
        fyv[s] = ys - y0f;
        float sx = axl + wxv[r];
        float x0f = floorf(sx);
        fxv[s] = sx - x0f;
        uv[s] = rpe8[(((int)y0f) << 6) + (int)x0f];
      }
    }

    // ---- S phase: 4 QK^T MFMAs (waits only on kc)
    f32x4 S[4];
#pragma unroll
    for (int jt = 0; jt < 4; jt++) {
      f32x4 z = {};
      S[jt] = __builtin_amdgcn_mfma_f32_16x16x32_bf16(kc[jt], aq, z, 0, 0, 0);
    }

    // ---- decode + exp2 + pack + P write (after all gathers issued)
#pragma unroll
    for (int jt = 0; jt < 4; jt++) {
      float pv[4];
#pragma unroll
      for (int r = 0; r < 4; r++) {
        int s = (jt << 2) + r;
        float g00, g10, g01, g11;
        unpack_fp8_quad(uv[s], g00, g10, g01, g11);
        float h0 = fmaf(fxv[s], g01 - g00, g00);
        float h1 = fmaf(fxv[s], g11 - g10, g10);
        float bias = fmaf(fyv[s], h1 - h0, h0);
        pv[r] = exp2_fast(S[jt][r] + bias);
      }
      unsigned p0 = pk2bf(pv[0], pv[1]);
      unsigned p1 = pk2bf(pv[2], pv[3]);
      int wb = (pwrow + (jt << 5) + (quad << 3)) ^ swz;
      *(uint2*)(pw + wb) = make_uint2(p0, p1);
    }

    // ---- P A-frags: lane l16 = i, quad = j-chunk (8 j's each)
    bf16x8 pa0 = *(const bf16x8*)(pw + ((pwrow + (quad << 4)) ^ swz));
    bf16x8 pa1 = *(const bf16x8*)(pw + ((pwrow + 64 + (quad << 4)) ^ swz));

    // ---- PV with this kt's V frags (vmcnt drains here)
#pragma unroll
    for (int dt = 0; dt < 2; dt++) {
      Oacc[dt] = __builtin_amdgcn_mfma_f32_16x16x32_bf16(pa0, vc[dt * 2],     Oacc[dt], 0, 0, 0);
      Oacc[dt] = __builtin_amdgcn_mfma_f32_16x16x32_bf16(pa1, vc[dt * 2 + 1], Oacc[dt], 0, 0, 0);
    }
    lacc = __builtin_amdgcn_mfma_f32_16x16x32_bf16(pa0, vones, lacc, 0, 0, 0);
    lacc = __builtin_amdgcn_mfma_f32_16x16x32_bf16(pa1, vones, lacc, 0, 0, 0);
  }

  // ---- epilogue -> ao bf16 (rows = i = row0 + quad*4 + r, cols = d)
#pragma unroll
  for (int r = 0; r < 4; r++) {
    float inv = 1.f / lacc[r];
    int row = row0 + (quad << 2) + r;
#pragma unroll
    for (int dt = 0; dt < 2; dt++) {
      ao[(size_t)((b << 10) + row) * 256 + (h << 5) + (dt << 4) + l16] =
          f2bf(Oacc[dt][r] * inv);
    }
  }
}

// ---------------------------------------------------------------------------
extern "C" void kernel_launch(void* const* d_in, const int* in_sizes, int n_in,
                              void* d_out, int out_size, void* d_ws, size_t ws_size,
                              hipStream_t stream) {
  (void)in_sizes; (void)n_in; (void)out_size; (void)ws_size;
  const float* x      = (const float*)d_in[0];
  const float* Wq     = (const float*)d_in[1];
  const float* Wkv    = (const float*)d_in[2];
  const float* conv_w = (const float*)d_in[3];
  const float* conv_b = (const float*)d_in[4];
  const float* ln_g   = (const float*)d_in[5];
  const float* ln_b   = (const float*)d_in[6];
  const float* Woff   = (const float*)d_in[7];
  const float* rpe    = (const float*)d_in[8];
  const float* Wout   = (const float*)d_in[9];
  const float* bout   = (const float*)d_in[10];
  float* out = (float*)d_out;

  float* ws    = (float*)d_ws;
  float* q     = ws;                       // 2,097,152 f32
  float* pos   = ws + 2097152;             //    32,768 f32
  short* kb    = (short*)(ws + 2129920);   // 8192*256 bf16 (K)
  short* vtb   = (short*)(ws + 3178496);   // 8*256*1024 bf16 (V^T [b][d][j])
  short* xsb   = (short*)(ws + 4227072);   // 8192*256 bf16
  short* aob   = (short*)(ws + 5275648);   // 8192*256 bf16
  short* Wkvt  = (short*)(ws + 6324224);   // 512*256 bf16
  short* Woutt = (short*)(ws + 6389760);   // 256*256 bf16
  short* Wqt   = (short*)(ws + 6422528);   // 256*256 bf16

  prep_weights<<<1024, 256, 0, stream>>>(Wkv, Wout, Wq, Wkvt, Woutt, Wqt);
  // 1. q = x @ Wq (bf16 MFMA, f32 A staged+converted, f32 out)
  gemm_bf16<<<dim3(4, 128), 256, 0, stream>>>(nullptr, x, Wqt, q, nullptr, nullptr, 256, nullptr);
  // 2+3. conv + LN + GELU + Woff + tanh -> pos, fused grid_sample -> xs
  conv_pos_sample_kernel<<<4096, 256, 0, stream>>>(q, conv_w, conv_b, ln_g, ln_b,
                                                   Woff, pos, xsb);
  // 4. kv = xs @ Wkv: K -> kb (row-major), V -> vtb (transposed epilogue)
  gemm_bf16<<<dim3(8, 128), 256, 0, stream>>>(xsb, nullptr, Wkvt, nullptr, kb, nullptr, 256, vtb);
  // 5. fused attention v8 (batched gathers, posAll once) -> ao (bf16)
  attn_kernel<<<dim3(16, 8, 8), 256, 0, stream>>>(q, kb, vtb, pos, rpe, aob);
  // 6. out = ao @ Wout + bout (bf16 MFMA, f32 out)
  gemm_bf16<<<dim3(4, 128), 256, 0, stream>>>(aob, nullptr, Woutt, out, nullptr, bout, 256, nullptr);
}

// Round 8
// 233.817 us; speedup vs baseline: 1.8676x; 1.0692x over previous
//
#include <hip/hip_runtime.h>
#include <hip/hip_bf16.h>
#include <hip/hip_fp16.h>
#include <hip/hip_fp8.h>

// DeformableAttention on MI355X.
// prep(weights^T bf16) -> gemm_bf16(q) -> fused conv+LN+GELU+pos+sample ->
// gemm_bf16(kv) -> fused flash-attn v9 (round-1 proven structure: 1 head/blk,
// grid 1024, cooperative V-stage, unswapped QK^T with shared y-chains;
// + strength-reduced per-kt pointers, + K/MFMA issued before bias math)
// -> gemm_bf16(out,+bias)

#define EPS_ 1e-5f
#define ASCALE 0.17677669529663687f      // 1/sqrt(32)
#define LOG2E  1.4426950408889634f

typedef __attribute__((ext_vector_type(8))) short bf16x8;
typedef __attribute__((ext_vector_type(4))) float f32x4;

__device__ __forceinline__ short f2bf(float f) {
  union { float f; unsigned u; } v; v.f = f;
  unsigned r = (v.u + 0x7fffu + ((v.u >> 16) & 1u)) >> 16;  // RNE
  return (short)r;
}
__device__ __forceinline__ unsigned pk2bf(float a, float b) {
  union { __hip_bfloat162 h; unsigned u; } v;
  v.h = __float22bfloat162_rn(make_float2(a, b));
  return v.u;
}
__device__ __forceinline__ float exp2_fast(float x) {
  return __builtin_amdgcn_exp2f(x);
}

// ---------------------------------------------------------------------------
// Weight prep: Wkvt[n][k]=bf16(Wkv[k][n]); Woutt, Wqt likewise.
// ---------------------------------------------------------------------------
__global__ __launch_bounds__(256) void prep_weights(
    const float* __restrict__ Wkv, const float* __restrict__ Wout,
    const float* __restrict__ Wq, short* __restrict__ Wkvt,
    short* __restrict__ Woutt, short* __restrict__ Wqt)
{
  int bid = blockIdx.x, k = threadIdx.x;
  if (bid < 512) Wkvt[bid * 256 + k] = f2bf(Wkv[k * 512 + bid]);
  else if (bid < 768) { int n = bid - 512; Woutt[n * 256 + k] = f2bf(Wout[k * 256 + n]); }
  else { int n = bid - 768; Wqt[n * 256 + k] = f2bf(Wq[k * 256 + n]); }
}

// ---------------------------------------------------------------------------
// bf16 MFMA GEMM: C[M,N] = A[M,256] @ Bt[N,256]^T (+bias), with prefetch.
// ---------------------------------------------------------------------------
__global__ __launch_bounds__(256) void gemm_bf16(
    const short* __restrict__ Ab, const float* __restrict__ Af,
    const short* __restrict__ Bt,
    float* __restrict__ Cf, short* __restrict__ Cb,
    const float* __restrict__ bias, int N)
{
  __shared__ __align__(16) short As[64 * 40];
  __shared__ __align__(16) short Bs[64 * 40];
  const int t = threadIdx.x;
  const int n0 = blockIdx.x << 6, m0 = blockIdx.y << 6;
  const int wv = t >> 6, l16 = t & 15, quad = (t & 63) >> 4;
  const int row = t >> 2, koff = (t & 3) << 3;

  auto loadA = [&](int k0) -> bf16x8 {
    if (Af) {
      const float* src = &Af[(size_t)(m0 + row) * 256 + k0 + koff];
      float4 f0 = *(const float4*)src;
      float4 f1 = *(const float4*)(src + 4);
      union { unsigned u[4]; bf16x8 v; } c;
      c.u[0] = pk2bf(f0.x, f0.y); c.u[1] = pk2bf(f0.z, f0.w);
      c.u[2] = pk2bf(f1.x, f1.y); c.u[3] = pk2bf(f1.z, f1.w);
      return c.v;
    }
    return *(const bf16x8*)&Ab[(size_t)(m0 + row) * 256 + k0 + koff];
  };

  f32x4 acc[4] = {};
  bf16x8 av = loadA(0);
  bf16x8 bv = *(const bf16x8*)&Bt[(size_t)(n0 + row) * 256 + koff];
  for (int k0 = 0; k0 < 256; k0 += 32) {
    __syncthreads();  // prior-iter frag reads done before overwrite
    *(bf16x8*)&As[row * 40 + koff] = av;
    *(bf16x8*)&Bs[row * 40 + koff] = bv;
    __syncthreads();
    if (k0 + 32 < 256) {  // prefetch next chunk before MFMA section
      av = loadA(k0 + 32);
      bv = *(const bf16x8*)&Bt[(size_t)(n0 + row) * 256 + k0 + 32 + koff];
    }
    bf16x8 a = *(const bf16x8*)&As[((wv << 4) + l16) * 40 + (quad << 3)];
#pragma unroll
    for (int jt = 0; jt < 4; jt++) {
      bf16x8 bb = *(const bf16x8*)&Bs[((jt << 4) + l16) * 40 + (quad << 3)];
      acc[jt] = __builtin_amdgcn_mfma_f32_16x16x32_bf16(a, bb, acc[jt], 0, 0, 0);
    }
  }
#pragma unroll
  for (int jt = 0; jt < 4; jt++) {
#pragma unroll
    for (int r = 0; r < 4; r++) {
      int mrow = m0 + (wv << 4) + (quad << 2) + r;
      int ncol = n0 + (jt << 4) + l16;
      float v = acc[jt][r];
      if (bias) v += bias[ncol];
      if (Cf) Cf[(size_t)mrow * N + ncol] = v;
      else    Cb[(size_t)mrow * N + ncol] = f2bf(v);
    }
  }
}

// ---------------------------------------------------------------------------
// Fused: conv5x5 depthwise + LN(128) + GELU + @Woff + tanh -> pos, then
// grid_sample of this pixel's group channels -> xs (bf16). Wave per (b,g,pix).
// ---------------------------------------------------------------------------
__global__ __launch_bounds__(256) void conv_pos_sample_kernel(
    const float* __restrict__ q, const float* __restrict__ conv_w,
    const float* __restrict__ conv_b, const float* __restrict__ ln_g,
    const float* __restrict__ ln_b, const float* __restrict__ Woff,
    float* __restrict__ pos, short* __restrict__ xsb)
{
  const int p = (blockIdx.x << 2) + (threadIdx.x >> 6);
  const int lane = threadIdx.x & 63;
  const int bg = p >> 10, pix = p & 1023;
  const int hh = pix >> 5, ww = pix & 31;
  const int b = bg >> 1, g = bg & 1;
  const int c0 = lane << 1;

  float2 cb = *(const float2*)&conv_b[c0];
  float a0 = cb.x, a1 = cb.y;
  const float* w0 = conv_w + c0 * 25;
  const float* w1 = w0 + 25;
#pragma unroll
  for (int dy = 0; dy < 5; dy++) {
    int y = hh + dy - 2;
    if ((unsigned)y < 32u) {
#pragma unroll
      for (int dx = 0; dx < 5; dx++) {
        int x = ww + dx - 2;
        if ((unsigned)x < 32u) {
          float2 qv = *(const float2*)&q[(size_t)((b << 10) + (y << 5) + x) * 256 + (g << 7) + c0];
          a0 = fmaf(qv.x, w0[dy * 5 + dx], a0);
          a1 = fmaf(qv.y, w1[dy * 5 + dx], a1);
        }
      }
    }
  }
  float s1 = a0 + a1, s2 = a0 * a0 + a1 * a1;
#pragma unroll
  for (int o = 32; o; o >>= 1) { s1 += __shfl_xor(s1, o); s2 += __shfl_xor(s2, o); }
  float mu = s1 * (1.f / 128.f);
  float inv = rsqrtf(fmaf(-mu, mu, s2 * (1.f / 128.f)) + EPS_);
  float2 lg = *(const float2*)&ln_g[c0];
  float2 lb = *(const float2*)&ln_b[c0];
  float v0 = (a0 - mu) * inv * lg.x + lb.x;
  float v1 = (a1 - mu) * inv * lg.y + lb.y;
  float ge0 = 0.5f * v0 * (1.f + erff(v0 * 0.70710678118654752f));
  float ge1 = 0.5f * v1 * (1.f + erff(v1 * 0.70710678118654752f));
  float2 W0 = *(const float2*)&Woff[c0 * 2];
  float2 W1 = *(const float2*)&Woff[c0 * 2 + 2];
  float o0 = ge0 * W0.x + ge1 * W1.x;
  float o1 = ge0 * W0.y + ge1 * W1.y;
#pragma unroll
  for (int o = 32; o; o >>= 1) { o0 += __shfl_xor(o0, o); o1 += __shfl_xor(o1, o); }
  float py = tanhf(o0) * 0.0625f + ((hh + 0.5f) * 0.0625f - 1.f);
  float px = tanhf(o1) * 0.0625f + ((ww + 0.5f) * 0.0625f - 1.f);
  if (lane == 0)
    ((float2*)pos)[(bg << 10) + pix] = make_float2(py, px);

  float x = (px + 1.f) * 15.5f;
  float y = (py + 1.f) * 15.5f;
  float x0f = floorf(x), y0f = floorf(y);
  int ix0 = (int)x0f, iy0 = (int)y0f;
  float fx = x - x0f, fy = y - y0f;
  float ac0 = 0.f, ac1 = 0.f;
#pragma unroll
  for (int dy = 0; dy < 2; dy++) {
#pragma unroll
    for (int dx = 0; dx < 2; dx++) {
      int yi = iy0 + dy, xi = ix0 + dx;
      float w = (dy ? fy : 1.f - fy) * (dx ? fx : 1.f - fx);
      if ((unsigned)yi < 32u && (unsigned)xi < 32u) {
        float2 qv = *(const float2*)&q[(size_t)((b << 10) + (yi << 5) + xi) * 256 + (g << 7) + c0];
        ac0 = fmaf(w, qv.x, ac0);
        ac1 = fmaf(w, qv.y, ac1);
      }
    }
  }
  *(unsigned*)&xsb[(size_t)((b << 10) + pix) * 256 + (g << 7) + c0] = pk2bf(ac0, ac1);
}

// ---------------------------------------------------------------------------
// Fused attention v9 = round-1 structure + surgical edits.
// One block = (64-row i-tile, head, batch), grid 1024, ~30 KB LDS ->
// 4 blocks/CU.  fp8 rpe quad table (1 ds_read_b32/sample for 4 taps).
// K/Q direct from global; V cooperatively LDS-staged; wave-local P;
// fixed-m softmax, l via ones-MFMA.  Edits vs round-1:
//  (1) strength-reduced per-kt pointers (K/V/pos advance by constants);
//  (2) 4 K-loads + 4 QK^T MFMAs issued BEFORE the bias-sample math;
//      4 posT reads + y-chains hoisted ahead of the 16 x/gather/decodes.
// ---------------------------------------------------------------------------
__global__ __launch_bounds__(256, 4) void attn_kernel(
    const float* __restrict__ q, const short* __restrict__ kvb,
    const float* __restrict__ pos, const float* __restrict__ rpe,
    short* __restrict__ ao)
{
  const int it = blockIdx.x, h = blockIdx.y, b = blockIdx.z;
  const int g = h >> 2, t = threadIdx.x;
  const int wv = t >> 6, l16 = t & 15, quad = (t & 63) >> 4;

  __shared__ __align__(16) short PL[64 * 72];     // P (wave-local rows)
  __shared__ __align__(16) short Vt[32 * 68];     // V^T [d][j]
  __shared__ float2 posT[64];                     // (-15.5*py, -15.5*px)
  __shared__ __align__(16) unsigned rpe8[64 * 64];  // fp8 quad per point

  // ---- stage fp8 rpe quad table over the reachable window (origin +31).
  {
    const float* rp = rpe + h * 3969;
    for (int i = t; i < 4096; i += 256) {
      int ty = i >> 6, tx = i & 63;
      float v00 = 0.f, v10 = 0.f, v01 = 0.f, v11 = 0.f;
      if (tx <= 62) {
        if (ty <= 62) v00 = rp[ty * 63 + tx] * LOG2E;
        if (ty <= 61) v10 = rp[(ty + 1) * 63 + tx] * LOG2E;
      }
      if (tx <= 61) {
        if (ty <= 62) v01 = rp[ty * 63 + tx + 1] * LOG2E;
        if (ty <= 61) v11 = rp[(ty + 1) * 63 + tx + 1] * LOG2E;
      }
      __hip_fp8x2_e4m3 elo(make_float2(v00, v10));   // y-pair at x0
      __hip_fp8x2_e4m3 ehi(make_float2(v01, v11));   // y-pair at x0+1
      rpe8[i] = (unsigned)(unsigned short)elo.__x |
                ((unsigned)(unsigned short)ehi.__x << 16);
    }
  }

  // ---- Q A-frag from global (once), scaled by ASCALE*LOG2E
  const int row0 = (it << 6) + (wv << 4);
  bf16x8 aq;
  {
    const float* src = q + (size_t)((b << 10) + row0 + l16) * 256 + (h << 5) + (quad << 3);
    float4 f0 = *(const float4*)src;
    float4 f1 = *(const float4*)(src + 4);
    const float sc = ASCALE * LOG2E;
    union { unsigned u[4]; bf16x8 v; } c;
    c.u[0] = pk2bf(f0.x * sc, f0.y * sc); c.u[1] = pk2bf(f0.z * sc, f0.w * sc);
    c.u[2] = pk2bf(f1.x * sc, f1.y * sc); c.u[3] = pk2bf(f1.z * sc, f1.w * sc);
    aq = c.v;
  }

  // sampling coords (origin +31): wave's 16 rows share one raster row
  const float ayc = 15.5f * (((row0 >> 5) + 0.5f) * 0.0625f - 1.f) + 31.f;
  float ax[4];
#pragma unroll
  for (int r = 0; r < 4; r++) {
    int ix = (row0 & 31) + (quad << 2) + r;
    ax[r] = 15.5f * ((ix + 0.5f) * 0.0625f - 1.f) + 31.f;
  }

  bf16x8 vones;
#pragma unroll
  for (int i = 0; i < 8; i++) vones[i] = (short)0x3F80;  // bf16 1.0

  // ---- strength-reduced pointer bases (advance by constants per kt)
  const int vj = t & 63, vc = t >> 6;
  const short* vsrc = kvb + (size_t)((b << 10) + vj) * 512 + 256 + (h << 5) + (vc << 3);
  const short* ksrc = kvb + (size_t)((b << 10) + l16) * 512 + (h << 5) + (quad << 3);
  const float2* psrc = (const float2*)pos + (((b << 1) + g) << 10) + t;

  f32x4 Oacc[2] = {};
  f32x4 lacc = {};

  for (int kt = 0; kt < 16; kt++) {
    __syncthreads();  // [b1] prior PV reads of Vt/posT done
    // ---- stage V^T: thread (j = t&63, c = t>>6) -> d = c*8..c*8+7
    {
      bf16x8 vv = *(const bf16x8*)vsrc;
#pragma unroll
      for (int k2 = 0; k2 < 8; k2++) Vt[((vc << 3) + k2) * 68 + vj] = vv[k2];
    }
    if (t < 64) {
      float2 pp = *psrc;
      posT[t] = make_float2(-15.5f * pp.x, -15.5f * pp.y);
    }
    __syncthreads();  // [b2]

    // ---- QK^T first: 4 K B-frags from global (L1) + 4 MFMA, before bias
    f32x4 S[4];
#pragma unroll
    for (int jt = 0; jt < 4; jt++) {
      bf16x8 bk = *(const bf16x8*)(ksrc + (size_t)jt * 8192);
      f32x4 z = {};
      S[jt] = __builtin_amdgcn_mfma_f32_16x16x32_bf16(aq, bk, z, 0, 0, 0);
    }

    // ---- y-chains for the 4 j's (posT broadcast reads), hoisted
    float fyv[4];
    int ybv[4];
    float wyv[4];
#pragma unroll
    for (int jt = 0; jt < 4; jt++) {
      float2 bv = posT[(jt << 4) + l16];
      float ys = ayc + bv.x;
      float y0f = floorf(ys);
      fyv[jt] = ys - y0f;
      ybv[jt] = (int)y0f << 6;
      wyv[jt] = bv.y;
    }

    // ---- bias sample + p = exp2(S+bias), per jt (x-chain + gather + decode)
    unsigned pu[4][2];
#pragma unroll
    for (int jt = 0; jt < 4; jt++) {
      float fy = fyv[jt];
      int ybase = ybv[jt];
      float pv[4];
#pragma unroll
      for (int r = 0; r < 4; r++) {
        float sx = ax[r] + wyv[jt];
        float x0f = floorf(sx);
        float fx = sx - x0f;
        unsigned u = rpe8[ybase + (int)x0f];
        __hip_fp8x2_e4m3 plo, phi;
        plo.__x = (__hip_fp8x2_storage_t)(unsigned short)(u & 0xffffu);
        phi.__x = (__hip_fp8x2_storage_t)(unsigned short)(u >> 16);
        float2 ga = (float2)plo;   // (g00, g10)
        float2 gb = (float2)phi;   // (g01, g11)
        float h0 = fmaf(fx, gb.x - ga.x, ga.x);
        float h1 = fmaf(fx, gb.y - ga.y, ga.y);
        float bias = fmaf(fy, h1 - h0, h0);
        pv[r] = exp2_fast(S[jt][r] + bias);
      }
      pu[jt][0] = pk2bf(pv[0], pv[1]);
      pu[jt][1] = pk2bf(pv[2], pv[3]);
    }

    // ---- wave-local P write -> A-frag read -> PV + l (no barrier)
#pragma unroll
    for (int jt = 0; jt < 4; jt++) {
      int cb = (jt << 4) + l16;
      int rb = ((wv << 4) + (quad << 2)) * 72 + cb;
      PL[rb]       = (short)(pu[jt][0] & 0xffff);
      PL[rb + 72]  = (short)(pu[jt][0] >> 16);
      PL[rb + 144] = (short)(pu[jt][1] & 0xffff);
      PL[rb + 216] = (short)(pu[jt][1] >> 16);
    }
    bf16x8 pa0 = *(const bf16x8*)&PL[((wv << 4) + l16) * 72 + (quad << 3)];
    bf16x8 pa1 = *(const bf16x8*)&PL[((wv << 4) + l16) * 72 + 32 + (quad << 3)];
#pragma unroll
    for (int dt = 0; dt < 2; dt++) {
      bf16x8 vb0 = *(const bf16x8*)&Vt[((dt << 4) + l16) * 68 + (quad << 3)];
      bf16x8 vb1 = *(const bf16x8*)&Vt[((dt << 4) + l16) * 68 + 32 + (quad << 3)];
      Oacc[dt] = __builtin_amdgcn_mfma_f32_16x16x32_bf16(pa0, vb0, Oacc[dt], 0, 0, 0);
      Oacc[dt] = __builtin_amdgcn_mfma_f32_16x16x32_bf16(pa1, vb1, Oacc[dt], 0, 0, 0);
    }
    lacc = __builtin_amdgcn_mfma_f32_16x16x32_bf16(pa0, vones, lacc, 0, 0, 0);
    lacc = __builtin_amdgcn_mfma_f32_16x16x32_bf16(pa1, vones, lacc, 0, 0, 0);

    // advance strength-reduced pointers (64 rows * 512 shorts; 64 float2)
    vsrc += 32768; ksrc += 32768; psrc += 64;
  }

  // ---- epilogue -> ao bf16
#pragma unroll
  for (int r = 0; r < 4; r++) {
    float inv = 1.f / lacc[r];
    int row = row0 + (quad << 2) + r;
#pragma unroll
    for (int dt = 0; dt < 2; dt++) {
      ao[(size_t)((b << 10) + row) * 256 + (h << 5) + (dt << 4) + l16] =
          f2bf(Oacc[dt][r] * inv);
    }
  }
}

// ---------------------------------------------------------------------------
extern "C" void kernel_launch(void* const* d_in, const int* in_sizes, int n_in,
                              void* d_out, int out_size, void* d_ws, size_t ws_size,
                              hipStream_t stream) {
  (void)in_sizes; (void)n_in; (void)out_size; (void)ws_size;
  const float* x      = (const float*)d_in[0];
  const float* Wq     = (const float*)d_in[1];
  const float* Wkv    = (const float*)d_in[2];
  const float* conv_w = (const float*)d_in[3];
  const float* conv_b = (const float*)d_in[4];
  const float* ln_g   = (const float*)d_in[5];
  const float* ln_b   = (const float*)d_in[6];
  const float* Woff   = (const float*)d_in[7];
  const float* rpe    = (const float*)d_in[8];
  const float* Wout   = (const float*)d_in[9];
  const float* bout   = (const float*)d_in[10];
  float* out = (float*)d_out;

  float* ws    = (float*)d_ws;
  float* q     = ws;                       // 2,097,152 f32
  float* pos   = ws + 2097152;             //    32,768 f32
  short* kvb   = (short*)(ws + 2129920);   // 8192*512 bf16
  short* xsb   = (short*)(ws + 4227072);   // 8192*256 bf16
  short* aob   = (short*)(ws + 5275648);   // 8192*256 bf16
  short* Wkvt  = (short*)(ws + 6324224);   // 512*256 bf16
  short* Woutt = (short*)(ws + 6389760);   // 256*256 bf16
  short* Wqt   = (short*)(ws + 6422528);   // 256*256 bf16

  prep_weights<<<1024, 256, 0, stream>>>(Wkv, Wout, Wq, Wkvt, Woutt, Wqt);
  // 1. q = x @ Wq (bf16 MFMA, f32 A staged+converted, f32 out)
  gemm_bf16<<<dim3(4, 128), 256, 0, stream>>>(nullptr, x, Wqt, q, nullptr, nullptr, 256);
  // 2+3. conv + LN + GELU + Woff + tanh -> pos, fused grid_sample -> xs
  conv_pos_sample_kernel<<<4096, 256, 0, stream>>>(q, conv_w, conv_b, ln_g, ln_b,
                                                   Woff, pos, xsb);
  // 4. kv = xs @ Wkv (bf16 MFMA, bf16 out)
  gemm_bf16<<<dim3(8, 128), 256, 0, stream>>>(xsb, nullptr, Wkvt, nullptr, kvb, nullptr, 512);
  // 5. fused attention v9 (round-1 structure + surgical edits) -> ao (bf16)
  attn_kernel<<<dim3(16, 8, 8), 256, 0, stream>>>(q, kvb, pos, rpe, aob);
  // 6. out = ao @ Wout + bout (bf16 MFMA, f32 out)
  gemm_bf16<<<dim3(4, 128), 256, 0, stream>>>(aob, nullptr, Woutt, out, nullptr, bout, 256);
}